// Round 4
// baseline (347.360 us; speedup 1.0000x reference)
//
#include <hip/hip_runtime.h>
#include <hip/hip_bf16.h>

// CGCNN: B=16, N=1024, M=12, F=64, BF=128, 3 conv layers.
// R4: layer-invariant bond GEMM for ALL 3 layers in one HBM-bound pass
// (bond read once, core stored bf16), feature-interleaved layouts so the
// per-layer epilogue is fully coalesced, barrier-free GEMM inner loop.
// Interleave: g = mcol*4 + ct  <->  f = ct*16 + mcol   (mcol=g>>2, ct=g&3)

#define BB 16
#define NN 1024
#define MM 12
#define FF 64
#define RT (BB * NN * MM)     // 196608 bond rows
#define S_BN 0.99950037f      // 1/sqrt(1+1e-3)

typedef __attribute__((ext_vector_type(8))) short bf16x8;
typedef __attribute__((ext_vector_type(4))) float f32x4;

static __device__ __forceinline__ unsigned short f2bf(float f) {
    union { float f; unsigned u; } c; c.f = f;
    unsigned r = c.u + 0x7fff + ((c.u >> 16) & 1);   // RNE
    return (unsigned short)(r >> 16);
}
static __device__ __forceinline__ float bf2f(unsigned short s) {
    union { unsigned u; float f; } c; c.u = ((unsigned)s) << 16;
    return c.f;
}
// permutation helpers: g in 0..63
__host__ __device__ __forceinline__ int fofg(int g) { return (g & 3) * 16 + (g >> 2); }

// ---- fold BN-a into core weight rows 0..127, double-permuted ---------------
// cwp[l][r][g] = cw[l][k(r)][f(g)] * gamma(f) * S_BN, k(r)= r<64? fofg(r):64+fofg(r-64)
__global__ void fold_w(const float* __restrict__ cw, const float* __restrict__ cb,
                       const float* __restrict__ g_,  const float* __restrict__ bab,
                       float* __restrict__ cwp, float* __restrict__ cbp) {
    int i = blockIdx.x * 256 + threadIdx.x;           // 3*128*64
    if (i >= 3 * 128 * 64) return;
    int g = i & 63;
    int r = (i >> 6) & 127;
    int l = i / (128 * 64);
    int f = fofg(g);
    int k = (r < 64) ? fofg(r) : 64 + fofg(r & 63);
    float gs = g_[l * 64 + f] * S_BN;
    cwp[i] = cw[(l * 256 + k) * 64 + f] * gs;
    if (r == 0)
        cbp[l * 64 + g] = cb[l * 64 + f] * gs + bab[l * 64 + f];
}

// ---- B panel in MFMA fragment order: 13 ct tiles (12 core + 1 filt) --------
// wT3[(((kc*13+ct)*64+lane)*8+j] = Bcol[ct*16+(lane&15)][kc*32+(lane>>4)*8+j]
__global__ void prep_wT3(const float* __restrict__ cw, const float* __restrict__ g_,
                         const float* __restrict__ fw, unsigned short* __restrict__ wT3) {
    int i = blockIdx.x * 256 + threadIdx.x;           // 4*13*64*8 = 26624
    if (i >= 26624) return;
    int j = i & 7;
    int t = i >> 3;
    int lane = t & 63;  t >>= 6;
    int ct = t % 13;
    int kc = t / 13;
    int c = ct * 16 + (lane & 15);
    int k = kc * 32 + (lane >> 4) * 8 + j;
    float v = 0.f;
    if (c < 192) {
        int l = c >> 6, f = c & 63;
        v = cw[(l * 256 + 128 + k) * 64 + f] * g_[l * 64 + f] * S_BN;
    } else if (c < 195) {
        v = fw[(c - 192) * 256 + 128 + k];
    }
    wT3[i] = f2bf(v);
}

// ---- embedding gather (interleaved x) --------------------------------------
__global__ void embed_k(const int* __restrict__ at, const float* __restrict__ emb,
                        float* __restrict__ x) {
    int i = blockIdx.x * 256 + threadIdx.x;
    int g = i & 63;
    int bn = i >> 6;
    x[i] = emb[at[bn] * FF + fofg(g)];
}

// ---- one-shot GEMM: core_{0,1,2} (bf16, interleaved) + filt_{0,1,2} --------
// grid 768 = 3 blocks/CU; wave owns rowtile-PAIRS (32 rows), no inner barriers
__global__ __launch_bounds__(256, 3) void gemm3(
    const float* __restrict__ bond, const unsigned short* __restrict__ wT3,
    unsigned short* __restrict__ core, float* __restrict__ filt) {
    __shared__ unsigned short bsh[26624];             // 53,248 B
    int tid = threadIdx.x;
    const float4* src = (const float4*)wT3;
    float4* dst = (float4*)bsh;
    #pragma unroll
    for (int i = 0; i < 13; i++) dst[tid + 256 * i] = src[tid + 256 * i];
    __syncthreads();

    int w = tid >> 6, lane = tid & 63;
    int mcol = lane & 15, q = lane >> 4;
    int wid = blockIdx.x * 4 + w;                     // < 3072

    #pragma unroll 1
    for (int it = 0; it < 2; it++) {
        int p = wid + it * 3072;                      // pair < 6144
        int rb = p * 32;

        // A fragments for both rowtiles (global -> reg, inline bf16 cvt)
        bf16x8 af[2][4];
        #pragma unroll
        for (int rt = 0; rt < 2; rt++) {
            const float* ap0 = bond + (size_t)(rb + rt * 16 + mcol) * 128 + q * 8;
            #pragma unroll
            for (int kc = 0; kc < 4; kc++) {
                float4 v0 = *(const float4*)(ap0 + kc * 32);
                float4 v1 = *(const float4*)(ap0 + kc * 32 + 4);
                bf16x8 a;
                a[0] = (short)f2bf(v0.x); a[1] = (short)f2bf(v0.y);
                a[2] = (short)f2bf(v0.z); a[3] = (short)f2bf(v0.w);
                a[4] = (short)f2bf(v1.x); a[5] = (short)f2bf(v1.y);
                a[6] = (short)f2bf(v1.z); a[7] = (short)f2bf(v1.w);
                af[rt][kc] = a;
            }
        }

        #pragma unroll
        for (int l = 0; l < 3; l++) {
            f32x4 acc[2][4];
            #pragma unroll
            for (int rt = 0; rt < 2; rt++)
                #pragma unroll
                for (int ct = 0; ct < 4; ct++)
                    acc[rt][ct] = (f32x4){0.f, 0.f, 0.f, 0.f};
            #pragma unroll
            for (int ct = 0; ct < 4; ct++)
                #pragma unroll
                for (int kc = 0; kc < 4; kc++) {
                    bf16x8 bf = *(const bf16x8*)&bsh[((kc * 13 + l * 4 + ct) * 64 + lane) * 8];
                    acc[0][ct] = __builtin_amdgcn_mfma_f32_16x16x32_bf16(af[0][kc], bf, acc[0][ct], 0, 0, 0);
                    acc[1][ct] = __builtin_amdgcn_mfma_f32_16x16x32_bf16(af[1][kc], bf, acc[1][ct], 0, 0, 0);
                }
            // store interleaved: core_l[row][mcol*4 + ct]
            #pragma unroll
            for (int rt = 0; rt < 2; rt++)
                #pragma unroll
                for (int r = 0; r < 4; r++) {
                    ushort4 h;
                    h.x = f2bf(acc[rt][0][r]); h.y = f2bf(acc[rt][1][r]);
                    h.z = f2bf(acc[rt][2][r]); h.w = f2bf(acc[rt][3][r]);
                    int row = rb + rt * 16 + q * 4 + r;
                    *(ushort4*)(core + ((size_t)l * RT + row) * 64 + mcol * 4) = h;
                }
        }
        // filt tile (ct = 12): col 192+l -> mcol == l
        f32x4 fa[2];
        fa[0] = (f32x4){0.f, 0.f, 0.f, 0.f};
        fa[1] = (f32x4){0.f, 0.f, 0.f, 0.f};
        #pragma unroll
        for (int kc = 0; kc < 4; kc++) {
            bf16x8 bf = *(const bf16x8*)&bsh[((kc * 13 + 12) * 64 + lane) * 8];
            fa[0] = __builtin_amdgcn_mfma_f32_16x16x32_bf16(af[0][kc], bf, fa[0], 0, 0, 0);
            fa[1] = __builtin_amdgcn_mfma_f32_16x16x32_bf16(af[1][kc], bf, fa[1], 0, 0, 0);
        }
        if (mcol < 3) {
            #pragma unroll
            for (int rt = 0; rt < 2; rt++)
                #pragma unroll
                for (int r = 0; r < 4; r++)
                    filt[(size_t)mcol * RT + rb + rt * 16 + q * 4 + r] = fa[rt][r];
        }
    }
}

// ---- per-atom projections (interleaved in/out; permuted weights) -----------
__global__ __launch_bounds__(256) void atomproj(
    const float* __restrict__ x, const float* __restrict__ cwp_l,
    const float* __restrict__ cbp_l, const float* __restrict__ fw_l,
    const float* __restrict__ fb_l,
    float* __restrict__ ys, float* __restrict__ yn,
    float* __restrict__ fs, float* __restrict__ fn) {
    __shared__ float wsh[128 * 64];
    __shared__ float xs[4][64];
    int tid = threadIdx.x, w = tid >> 6, lane = tid & 63;
    #pragma unroll
    for (int i = 0; i < 8; i++)
        ((float4*)wsh)[tid + 256 * i] = ((const float4*)cwp_l)[tid + 256 * i];
    int kl = fofg(lane);
    float fw1 = fw_l[kl], fw2 = fw_l[64 + kl];
    float cbv = cbp_l[lane], fbv = fb_l[0];
    __syncthreads();
    #pragma unroll 1
    for (int it = 0; it < 4; it++) {
        int row = (blockIdx.x * 4 + it) * 4 + w;
        float xl = x[(size_t)row * 64 + lane];
        xs[w][lane] = xl;
        float a1 = cbv, a2 = 0.f;
        #pragma unroll 16
        for (int k = 0; k < 64; k++) {
            float xv = xs[w][k];
            a1 += xv * wsh[k * 64 + lane];
            a2 += xv * wsh[(64 + k) * 64 + lane];
        }
        ys[(size_t)row * 64 + lane] = a1;
        yn[(size_t)row * 64 + lane] = a2;
        float p1 = xl * fw1, p2 = xl * fw2;
        #pragma unroll
        for (int off = 32; off; off >>= 1) {
            p1 += __shfl_xor(p1, off, 64);
            p2 += __shfl_xor(p2, off, 64);
        }
        if (lane == 0) { fs[row] = p1 + fbv; fn[row] = p2; }
    }
}

// ---- per-layer epilogue (all loads coalesced via interleave) ---------------
__global__ __launch_bounds__(256) void layer_ep(
    const float* __restrict__ x, const unsigned short* __restrict__ core_l,
    const float* __restrict__ filt_l, const int* __restrict__ nbr,
    const float* __restrict__ ys, const float* __restrict__ yn,
    const float* __restrict__ fs, const float* __restrict__ fn,
    const float* __restrict__ bbg, const float* __restrict__ bbb,
    float* __restrict__ xout) {
    int tid = threadIdx.x, w = tid >> 6, lane = tid & 63;
    int mcol = lane & 15, q = lane >> 4;
    int atom = blockIdx.x * 16 + w * 4 + q;
    int base = (atom >> 10) << 10;
    size_t rb = (size_t)atom * MM;

    int jv[MM];
    #pragma unroll
    for (int m = 0; m < MM; m++) jv[m] = nbr[rb + m];
    float lg[MM];
    float fsv = fs[atom];
    #pragma unroll
    for (int m = 0; m < MM; m++) lg[m] = filt_l[rb + m] + fsv + fn[base + jv[m]];
    float mx = -1e30f;
    #pragma unroll
    for (int m = 0; m < MM; m++) mx = fmaxf(mx, lg[m]);
    float sme = 0.f;
    #pragma unroll
    for (int m = 0; m < MM; m++) { lg[m] = __expf(lg[m] - mx); sme += lg[m]; }
    float inv = 1.f / (12.f * sme);

    float4 ysv = *(const float4*)(ys + (size_t)atom * 64 + mcol * 4);
    float sum[4] = {0.f, 0.f, 0.f, 0.f};
    #pragma unroll
    for (int m = 0; m < MM; m++) {
        ushort4 ch = *(const ushort4*)(core_l + (rb + m) * 64 + mcol * 4);
        float4 ynv = *(const float4*)(yn + (size_t)(base + jv[m]) * 64 + mcol * 4);
        float c0 = bf2f(ch.x) + ysv.x + ynv.x;
        float c1 = bf2f(ch.y) + ysv.y + ynv.y;
        float c2 = bf2f(ch.z) + ysv.z + ynv.z;
        float c3 = bf2f(ch.w) + ysv.w + ynv.w;
        sum[0] += lg[m] * fmaxf(c0, 0.f);
        sum[1] += lg[m] * fmaxf(c1, 0.f);
        sum[2] += lg[m] * fmaxf(c2, 0.f);
        sum[3] += lg[m] * fmaxf(c3, 0.f);
    }
    float4 xv = *(const float4*)(x + (size_t)atom * 64 + mcol * 4);
    float4 o;
    o.x = fmaxf(xv.x + bbg[mcol]      * (sum[0] * inv * S_BN) + bbb[mcol],      0.f);
    o.y = fmaxf(xv.y + bbg[16 + mcol] * (sum[1] * inv * S_BN) + bbb[16 + mcol], 0.f);
    o.z = fmaxf(xv.z + bbg[32 + mcol] * (sum[2] * inv * S_BN) + bbb[32 + mcol], 0.f);
    o.w = fmaxf(xv.w + bbg[48 + mcol] * (sum[3] * inv * S_BN) + bbb[48 + mcol], 0.f);
    *(float4*)(xout + (size_t)atom * 64 + mcol * 4) = o;
}

// ---- pooling gather + dense + relu (x interleaved -> out standard) ---------
__global__ __launch_bounds__(256) void final_k(
    const float* __restrict__ x, const int* __restrict__ tidx,
    const float* __restrict__ dw, const float* __restrict__ db,
    float* __restrict__ out) {
    __shared__ float xs[4][64];
    __shared__ float wsh[64 * 64];
    int tid = threadIdx.x;
    int w = tid >> 6, lane = tid & 63;
    const float4* src = (const float4*)dw;
    float4* dst = (float4*)wsh;
    #pragma unroll
    for (int i = 0; i < 4; i++) dst[tid + 256 * i] = src[tid + 256 * i];
    int row = blockIdx.x * 4 + w;
    int b = row >> 6;
    int t = tidx[row];
    float xv = x[((size_t)b * NN + t) * 64 + lane];   // interleaved feature fofg(lane)
    xs[w][lane] = fmaxf(xv, 0.f);
    __syncthreads();
    float a = db[lane];
    #pragma unroll
    for (int g = 0; g < 64; g++)
        a += xs[w][g] * wsh[fofg(g) * 64 + lane];
    out[row * 64 + lane] = fmaxf(a, 0.f);
}

extern "C" void kernel_launch(void* const* d_in, const int* in_sizes, int n_in,
                              void* d_out, int out_size, void* d_ws, size_t ws_size,
                              hipStream_t stream) {
    const int*   at   = (const int*)d_in[0];
    const float* bond = (const float*)d_in[1];
    const int*   nbr  = (const int*)d_in[2];
    const int*   tgt  = (const int*)d_in[3];
    const float* emb  = (const float*)d_in[4];
    const float* cw   = (const float*)d_in[5];
    const float* cb   = (const float*)d_in[6];
    const float* fw   = (const float*)d_in[7];
    const float* fb   = (const float*)d_in[8];
    const float* bag  = (const float*)d_in[9];
    const float* bab  = (const float*)d_in[10];
    const float* bbg  = (const float*)d_in[11];
    const float* bbb  = (const float*)d_in[12];
    const float* dw   = (const float*)d_in[13];
    const float* db   = (const float*)d_in[14];

    float* ws   = (float*)d_ws;
    float* xA   = ws;
    float* xB   = xA + (size_t)BB * NN * FF;          // 1,048,576 ea
    float* cwp  = xB + (size_t)BB * NN * FF;          // 3*128*64
    float* cbp  = cwp + 3 * 128 * 64;                 // 192
    float* ys   = cbp + 192;
    float* yn   = ys + (size_t)BB * NN * FF;
    float* fs   = yn + (size_t)BB * NN * FF;
    float* fn   = fs + (size_t)BB * NN;
    float* filt = fn + (size_t)BB * NN;               // 3*RT f32
    unsigned short* wT3  = (unsigned short*)(filt + 3 * (size_t)RT);  // 26624 bf16
    unsigned short* core = wT3 + 26624;               // 3*RT*64 bf16 (~75.5 MB)

    fold_w<<<(3 * 128 * 64 + 255) / 256, 256, 0, stream>>>(cw, cb, bag, bab, cwp, cbp);
    prep_wT3<<<104, 256, 0, stream>>>(cw, bag, fw, wT3);
    embed_k<<<(BB * NN * FF) / 256, 256, 0, stream>>>(at, emb, xA);
    gemm3<<<768, 256, 0, stream>>>(bond, wT3, core, filt);

    float* xin = xA;
    float* xout = xB;
    for (int l = 0; l < 3; l++) {
        atomproj<<<BB * NN / 16, 256, 0, stream>>>(
            xin, cwp + (size_t)l * 128 * 64, cbp + l * 64, fw + l * 256, fb + l,
            ys, yn, fs, fn);
        layer_ep<<<BB * NN / 16, 256, 0, stream>>>(
            xin, core + (size_t)l * RT * 64, filt + (size_t)l * RT, nbr,
            ys, yn, fs, fn, bbg + l * 64, bbb + l * 64, xout);
        float* t = xin; xin = xout; xout = t;
    }

    final_k<<<BB * 64 / 4, 256, 0, stream>>>(xin, tgt, dw, db, (float*)d_out);
}

// Round 5
// 295.425 us; speedup vs baseline: 1.1758x; 1.1758x over previous
//
#include <hip/hip_runtime.h>
#include <hip/hip_bf16.h>

// CGCNN: B=16, N=1024, M=12, F=64, BF=128, 3 conv layers.
// R5: fused per-layer conv (R3 architecture: no core materialization, bond
// L3-resident across layers) with the latency bugs fixed:
//   - grid 1024 (1 tile/block), NO barriers in the body (csh is wave-private)
//   - feature-interleaved layouts (R4) so every epilogue access is float4
//   - B-frags in registers, A-frags global->reg
// Interleave: g = mcol*4 + ct  <->  f = ct*16 + mcol

#define BB 16
#define NN 1024
#define MM 12
#define FF 64
#define S_BN 0.99950037f      // 1/sqrt(1+1e-3)
#define CSTR 68               // csh row stride (ushorts), mult of 4 for ushort4

typedef __attribute__((ext_vector_type(8))) short bf16x8;
typedef __attribute__((ext_vector_type(4))) float f32x4;

static __device__ __forceinline__ unsigned short f2bf(float f) {
    union { float f; unsigned u; } c; c.f = f;
    unsigned r = c.u + 0x7fff + ((c.u >> 16) & 1);   // RNE
    return (unsigned short)(r >> 16);
}
static __device__ __forceinline__ float bf2f(unsigned short s) {
    union { unsigned u; float f; } c; c.u = ((unsigned)s) << 16;
    return c.f;
}
__host__ __device__ __forceinline__ int fofg(int g) { return (g & 3) * 16 + (g >> 2); }

// ---- fold BN-a into core weight rows 0..127, double-permuted (R4) ----------
__global__ void fold_w(const float* __restrict__ cw, const float* __restrict__ cb,
                       const float* __restrict__ g_,  const float* __restrict__ bab,
                       float* __restrict__ cwp, float* __restrict__ cbp) {
    int i = blockIdx.x * 256 + threadIdx.x;           // 3*128*64
    if (i >= 3 * 128 * 64) return;
    int g = i & 63;
    int r = (i >> 6) & 127;
    int l = i / (128 * 64);
    int f = fofg(g);
    int k = (r < 64) ? fofg(r) : 64 + fofg(r & 63);
    float gs = g_[l * 64 + f] * S_BN;
    cwp[i] = cw[(l * 256 + k) * 64 + f] * gs;
    if (r == 0)
        cbp[l * 64 + g] = cb[l * 64 + f] * gs + bab[l * 64 + f];
}

// ---- per-layer B panel in MFMA fragment order (5 ct tiles, R3) -------------
// wT2[(((l*4+kc)*5+ct)*64+lane)*8+j] = Bcol[ct*16+(lane&15)][kc*32+(lane>>4)*8+j]
// col 0..63: folded core rows 128..255; col 64: filt rows 128..255; 65..79: 0
__global__ void prep_wT2(const float* __restrict__ cw, const float* __restrict__ g_,
                         const float* __restrict__ fw, unsigned short* __restrict__ wT2) {
    int i = blockIdx.x * 256 + threadIdx.x;           // 3*4*5*64*8 = 30720
    if (i >= 30720) return;
    int j = i & 7;
    int t = i >> 3;
    int lane = t & 63;  t >>= 6;
    int ct = t % 5;     t /= 5;
    int kc = t & 3;
    int l  = t >> 2;
    int col = ct * 16 + (lane & 15);
    int k   = kc * 32 + (lane >> 4) * 8 + j;
    float v = 0.f;
    if (col < 64)       v = cw[(l * 256 + 128 + k) * 64 + col] * g_[l * 64 + col] * S_BN;
    else if (col == 64) v = fw[l * 256 + 128 + k];
    wT2[i] = f2bf(v);
}

// ---- embedding gather (interleaved x) --------------------------------------
__global__ void embed_k(const int* __restrict__ at, const float* __restrict__ emb,
                        float* __restrict__ x) {
    int i = blockIdx.x * 256 + threadIdx.x;
    int g = i & 63;
    int bn = i >> 6;
    x[i] = emb[at[bn] * FF + fofg(g)];
}

// ---- per-atom projections (interleaved in/out; permuted weights) -----------
__global__ __launch_bounds__(256) void atomproj(
    const float* __restrict__ x, const float* __restrict__ cwp_l,
    const float* __restrict__ cbp_l, const float* __restrict__ fw_l,
    const float* __restrict__ fb_l,
    float* __restrict__ ys, float* __restrict__ yn,
    float* __restrict__ fs, float* __restrict__ fn) {
    __shared__ float wsh[128 * 64];
    __shared__ float xs[4][64];
    int tid = threadIdx.x, w = tid >> 6, lane = tid & 63;
    #pragma unroll
    for (int i = 0; i < 8; i++)
        ((float4*)wsh)[tid + 256 * i] = ((const float4*)cwp_l)[tid + 256 * i];
    int kl = fofg(lane);
    float fw1 = fw_l[kl], fw2 = fw_l[64 + kl];
    float cbv = cbp_l[lane], fbv = fb_l[0];
    __syncthreads();
    #pragma unroll 1
    for (int it = 0; it < 4; it++) {
        int row = (blockIdx.x * 4 + it) * 4 + w;
        float xl = x[(size_t)row * 64 + lane];
        xs[w][lane] = xl;
        float a1 = cbv, a2 = 0.f;
        #pragma unroll 16
        for (int k = 0; k < 64; k++) {
            float xv = xs[w][k];
            a1 += xv * wsh[k * 64 + lane];
            a2 += xv * wsh[(64 + k) * 64 + lane];
        }
        ys[(size_t)row * 64 + lane] = a1;
        yn[(size_t)row * 64 + lane] = a2;
        float p1 = xl * fw1, p2 = xl * fw2;
        #pragma unroll
        for (int off = 32; off; off >>= 1) {
            p1 += __shfl_xor(p1, off, 64);
            p2 += __shfl_xor(p2, off, 64);
        }
        if (lane == 0) { fs[row] = p1 + fbv; fn[row] = p2; }
    }
}

// ---- fused conv layer: bond@W (MFMA) + softmax + mean + BN-b + residual ----
// block = 16 atoms = 192 bond rows; wave owns 4 atoms (48 rows) end-to-end;
// NO barriers: csh/fltw are wave-private.
__global__ __launch_bounds__(256) void conv_fused(
    const float* __restrict__ bond, const unsigned short* __restrict__ wTl,
    const int* __restrict__ nbr, const float* __restrict__ x,
    const float* __restrict__ ys, const float* __restrict__ yn,
    const float* __restrict__ fs, const float* __restrict__ fn,
    const float* __restrict__ bbg, const float* __restrict__ bbb,
    float* __restrict__ xout) {
    __shared__ unsigned short csh[4][48 * CSTR];   // 26.1 KB core dump (bf16)
    __shared__ float fltw[4][48];                  // filt logits
    int tid = threadIdx.x, w = tid >> 6, lane = tid & 63;
    int mcol = lane & 15, q = lane >> 4;

    // B fragments in registers (20 frags = 80 VGPR), loaded once
    bf16x8 bw[4][5];
    #pragma unroll
    for (int kc = 0; kc < 4; kc++)
        #pragma unroll
        for (int ct = 0; ct < 5; ct++)
            bw[kc][ct] = *(const bf16x8*)(wTl + ((kc * 5 + ct) * 64 + lane) * 8);

    int rowbase = blockIdx.x * 192 + w * 48;

    #pragma unroll
    for (int rt = 0; rt < 3; rt++) {
        // A fragments for this rowtile (global -> reg, inline bf16 cvt)
        bf16x8 af[4];
        const float* ap0 = bond + (size_t)(rowbase + rt * 16 + mcol) * 128 + q * 8;
        #pragma unroll
        for (int kc = 0; kc < 4; kc++) {
            float4 v0 = *(const float4*)(ap0 + kc * 32);
            float4 v1 = *(const float4*)(ap0 + kc * 32 + 4);
            bf16x8 a;
            a[0] = (short)f2bf(v0.x); a[1] = (short)f2bf(v0.y);
            a[2] = (short)f2bf(v0.z); a[3] = (short)f2bf(v0.w);
            a[4] = (short)f2bf(v1.x); a[5] = (short)f2bf(v1.y);
            a[6] = (short)f2bf(v1.z); a[7] = (short)f2bf(v1.w);
            af[kc] = a;
        }
        f32x4 acc[5];
        #pragma unroll
        for (int ct = 0; ct < 5; ct++) acc[ct] = (f32x4){0.f, 0.f, 0.f, 0.f};
        #pragma unroll
        for (int kc = 0; kc < 4; kc++)
            #pragma unroll
            for (int ct = 0; ct < 5; ct++)
                acc[ct] = __builtin_amdgcn_mfma_f32_16x16x32_bf16(
                    af[kc], bw[kc][ct], acc[ct], 0, 0, 0);

        // dump C (row = rt*16 + q*4 + r) to wave-private LDS, interleaved cols
        #pragma unroll
        for (int r = 0; r < 4; r++) {
            int row = rt * 16 + q * 4 + r;
            ushort4 h;
            h.x = f2bf(acc[0][r]); h.y = f2bf(acc[1][r]);
            h.z = f2bf(acc[2][r]); h.w = f2bf(acc[3][r]);
            *(ushort4*)&csh[w][row * CSTR + mcol * 4] = h;
            if (mcol == 0) fltw[w][row] = acc[4][r];
        }
    }

    // epilogue: lane owns (atom = q, features f = ct*16 + mcol, ct=0..3)
    int atom = blockIdx.x * 16 + w * 4 + q;
    int base = (atom >> 10) << 10;
    size_t rb = (size_t)atom * MM;
    int jv[MM];
    #pragma unroll
    for (int m = 0; m < MM; m++) jv[m] = nbr[rb + m];
    float lg[MM];
    float fsv = fs[atom];
    #pragma unroll
    for (int m = 0; m < MM; m++)
        lg[m] = fltw[w][q * MM + m] + fsv + fn[base + jv[m]];
    float mx = -1e30f;
    #pragma unroll
    for (int m = 0; m < MM; m++) mx = fmaxf(mx, lg[m]);
    float sme = 0.f;
    #pragma unroll
    for (int m = 0; m < MM; m++) { lg[m] = __expf(lg[m] - mx); sme += lg[m]; }
    float inv = 1.f / (12.f * sme);

    float4 ysv = *(const float4*)(ys + (size_t)atom * 64 + mcol * 4);
    float sum0 = 0.f, sum1 = 0.f, sum2 = 0.f, sum3 = 0.f;
    #pragma unroll
    for (int m = 0; m < MM; m++) {
        ushort4 ch = *(const ushort4*)&csh[w][(q * MM + m) * CSTR + mcol * 4];
        float4 ynv = *(const float4*)(yn + (size_t)(base + jv[m]) * 64 + mcol * 4);
        sum0 += lg[m] * fmaxf(bf2f(ch.x) + ysv.x + ynv.x, 0.f);
        sum1 += lg[m] * fmaxf(bf2f(ch.y) + ysv.y + ynv.y, 0.f);
        sum2 += lg[m] * fmaxf(bf2f(ch.z) + ysv.z + ynv.z, 0.f);
        sum3 += lg[m] * fmaxf(bf2f(ch.w) + ysv.w + ynv.w, 0.f);
    }
    float4 xv = *(const float4*)(x + (size_t)atom * 64 + mcol * 4);
    float4 o;
    o.x = fmaxf(xv.x + bbg[mcol]      * (sum0 * inv * S_BN) + bbb[mcol],      0.f);
    o.y = fmaxf(xv.y + bbg[16 + mcol] * (sum1 * inv * S_BN) + bbb[16 + mcol], 0.f);
    o.z = fmaxf(xv.z + bbg[32 + mcol] * (sum2 * inv * S_BN) + bbb[32 + mcol], 0.f);
    o.w = fmaxf(xv.w + bbg[48 + mcol] * (sum3 * inv * S_BN) + bbb[48 + mcol], 0.f);
    *(float4*)(xout + (size_t)atom * 64 + mcol * 4) = o;
}

// ---- pooling gather + dense + relu (x interleaved -> out standard) ---------
__global__ __launch_bounds__(256) void final_k(
    const float* __restrict__ x, const int* __restrict__ tidx,
    const float* __restrict__ dw, const float* __restrict__ db,
    float* __restrict__ out) {
    __shared__ float xs[4][64];
    __shared__ float wsh[64 * 64];
    int tid = threadIdx.x;
    int w = tid >> 6, lane = tid & 63;
    const float4* src = (const float4*)dw;
    float4* dst = (float4*)wsh;
    #pragma unroll
    for (int i = 0; i < 4; i++) dst[tid + 256 * i] = src[tid + 256 * i];
    int row = blockIdx.x * 4 + w;
    int b = row >> 6;
    int t = tidx[row];
    float xv = x[((size_t)b * NN + t) * 64 + lane];   // feature fofg(lane)
    xs[w][lane] = fmaxf(xv, 0.f);
    __syncthreads();
    float a = db[lane];
    #pragma unroll
    for (int g = 0; g < 64; g++)
        a += xs[w][g] * wsh[fofg(g) * 64 + lane];
    out[row * 64 + lane] = fmaxf(a, 0.f);
}

extern "C" void kernel_launch(void* const* d_in, const int* in_sizes, int n_in,
                              void* d_out, int out_size, void* d_ws, size_t ws_size,
                              hipStream_t stream) {
    const int*   at   = (const int*)d_in[0];
    const float* bond = (const float*)d_in[1];
    const int*   nbr  = (const int*)d_in[2];
    const int*   tgt  = (const int*)d_in[3];
    const float* emb  = (const float*)d_in[4];
    const float* cw   = (const float*)d_in[5];
    const float* cb   = (const float*)d_in[6];
    const float* fw   = (const float*)d_in[7];
    const float* fb   = (const float*)d_in[8];
    const float* bag  = (const float*)d_in[9];
    const float* bab  = (const float*)d_in[10];
    const float* bbg  = (const float*)d_in[11];
    const float* bbb  = (const float*)d_in[12];
    const float* dw   = (const float*)d_in[13];
    const float* db   = (const float*)d_in[14];

    float* ws  = (float*)d_ws;
    float* xA  = ws;
    float* xB  = xA + (size_t)BB * NN * FF;
    float* cwp = xB + (size_t)BB * NN * FF;
    float* cbp = cwp + 3 * 128 * 64;
    float* ys  = cbp + 192;
    float* yn  = ys + (size_t)BB * NN * FF;
    float* fs  = yn + (size_t)BB * NN * FF;
    float* fn  = fs + (size_t)BB * NN;
    unsigned short* wT2 = (unsigned short*)(fn + (size_t)BB * NN);  // 30720 bf16
    // total ~17 MB

    fold_w<<<96, 256, 0, stream>>>(cw, cb, bag, bab, cwp, cbp);
    prep_wT2<<<120, 256, 0, stream>>>(cw, bag, fw, wT2);
    embed_k<<<(BB * NN * FF) / 256, 256, 0, stream>>>(at, emb, xA);

    float* xin = xA;
    float* xout = xB;
    for (int l = 0; l < 3; l++) {
        atomproj<<<BB * NN / 16, 256, 0, stream>>>(
            xin, cwp + (size_t)l * 128 * 64, cbp + l * 64, fw + l * 256, fb + l,
            ys, yn, fs, fn);
        conv_fused<<<BB * NN / 16, 256, 0, stream>>>(
            bond, wT2 + (size_t)l * 10240, nbr, xin,
            ys, yn, fs, fn, bbg + l * 64, bbb + l * 64, xout);
        float* t = xin; xin = xout; xout = t;
    }

    final_k<<<BB * 64 / 4, 256, 0, stream>>>(xin, tgt, dw, db, (float*)d_out);
}